// Round 3
// baseline (390.124 us; speedup 1.0000x reference)
//
#include <hip/hip_runtime.h>
#include <hip/hip_bf16.h>

constexpr int kD  = 1024;
constexpr int kH  = 16;
constexpr int kHD = 64;
constexpr int kS  = 64;
constexpr int kE  = 16;
constexpr int kB  = 32;
constexpr int kSB = kS * kB;   // 2048 (s,b) pairs

typedef __attribute__((ext_vector_type(8))) short bfvec8;   // 8 bf16 (4 VGPRs)
typedef __attribute__((ext_vector_type(4))) float fvec4;    // MFMA acc
typedef __attribute__((ext_vector_type(4))) int   ivec4;

struct __align__(8)  bf4  { __hip_bfloat16 v[4]; };
struct __align__(16) bf8v { __hip_bfloat16 v[8]; };

// ---------------- precompute kernel (folded: qs, cb, kb2, Wo->bf16) ----------------
// blocks    0..1023: qs[j]  = (Wq_in[j,:]·query + bq_in[j]) * 0.125
// blocks 1024..2047: cb[j]  = Wv_in[j,:]·bv_lin + bv_in[j]
// blocks 2048..3071: kb2[j] = Wk_in[j,:]·bk_lin + bk_in[j]
// blocks 3072..4095: Wobf row convert (f32 -> bf16)
__global__ __launch_bounds__(256) void k_pre(const float* __restrict__ Wq_in,
                                             const float* __restrict__ query,
                                             const float* __restrict__ bq_in,
                                             const float* __restrict__ Wv_in,
                                             const float* __restrict__ bv_lin,
                                             const float* __restrict__ bv_in,
                                             const float* __restrict__ Wk_in,
                                             const float* __restrict__ bk_lin,
                                             const float* __restrict__ bk_in,
                                             const float* __restrict__ Wo,
                                             float* __restrict__ qs,
                                             float* __restrict__ cb,
                                             float* __restrict__ kb2,
                                             __hip_bfloat16* __restrict__ Wobf) {
  int j = blockIdx.x, t = threadIdx.x;
  if (j >= 3072) {                 // Wo convert: one row per block, 4 elems/thread
    int i = (j - 3072) * kD + t * 4;
    float4 v = *(const float4*)(Wo + i);
    bf4 o;
    o.v[0] = __float2bfloat16(v.x); o.v[1] = __float2bfloat16(v.y);
    o.v[2] = __float2bfloat16(v.z); o.v[3] = __float2bfloat16(v.w);
    *(bf4*)(Wobf + i) = o;
    return;
  }
  const float *W, *vec, *bias;
  float scale;
  float* outp;
  int row;
  if (j < 1024)      { W = Wq_in; vec = query;  bias = bq_in; scale = 0.125f; outp = qs;  row = j; }
  else if (j < 2048) { W = Wv_in; vec = bv_lin; bias = bv_in; scale = 1.0f;   outp = cb;  row = j - 1024; }
  else               { W = Wk_in; vec = bk_lin; bias = bk_in; scale = 1.0f;   outp = kb2; row = j - 2048; }
  const float4* w4 = (const float4*)(W + (size_t)row * kD);
  const float4* v4 = (const float4*)vec;
  float4 a = w4[t], b = v4[t];
  float acc = a.x * b.x + a.y * b.y + a.z * b.z + a.w * b.w;
  #pragma unroll
  for (int o = 32; o >= 1; o >>= 1) acc += __shfl_xor(acc, o);
  __shared__ float red[4];
  if ((t & 63) == 0) red[t >> 6] = acc;
  __syncthreads();
  if (t == 0) outp[row] = (red[0] + red[1] + red[2] + red[3] + bias[row]) * scale;
}

// ---------------- U = qs-weighted rows of KK (bf16), plus cvec ----------------
// U[h,n] = sum_{j<64} qs[h*64+j] * KK[h*64+j, n]   (associativity: (qs@Wk_in)@Wk_lin)
// cvec[h] = sum_{j<64} qs[h*64+j] * kb2[h*64+j]
__global__ __launch_bounds__(256) void k_w2p(const float* __restrict__ qs,
                                             const __hip_bfloat16* __restrict__ KK,
                                             const float* __restrict__ kb2,
                                             __hip_bfloat16* __restrict__ Ubf,
                                             float* __restrict__ cvec) {
  int bq = blockIdx.x;                 // 64 blocks: h = bq>>2, n-chunk = (bq&3)*256
  int h = bq >> 2;
  int n = (bq & 3) * 256 + threadIdx.x;
  float acc = 0.f;
  #pragma unroll 8
  for (int j = 0; j < kHD; j++)
    acc = fmaf(qs[h * kHD + j], __bfloat162float(KK[(size_t)(h * kHD + j) * kD + n]), acc);
  Ubf[(size_t)h * kD + n] = __float2bfloat16(acc);
  if ((bq & 3) == 0 && threadIdx.x < 64) {
    int t = threadIdx.x;
    float v = qs[h * kHD + t] * kb2[h * kHD + t];
    #pragma unroll
    for (int o = 32; o >= 1; o >>= 1) v += __shfl_xor(v, o);
    if (t == 0) cvec[h] = v;
  }
}

// ---------------- fused attention: scores(MFMA) -> softmax -> eagg(MFMA) ----------------
// eagg change vs proven base: tiles processed in PAIRS (tt, tt+8). All 4 quads load
// useful A-data (quads 0,1 -> tile tt; quads 2,3 -> tile tt+8); the partner half is
// obtained with __shfl_xor(.,32). Wrong-half lanes land in MFMA k-slots 16..31 which
// multiply attn_b cols 16..31 == 0, so they are don't-care. Halves eagg LDS issues.

__device__ __forceinline__ void st4(__hip_bfloat16* dst, fvec4 a) {
  bf4 o;
  o.v[0] = __float2bfloat16(a[0]); o.v[1] = __float2bfloat16(a[1]);
  o.v[2] = __float2bfloat16(a[2]); o.v[3] = __float2bfloat16(a[3]);
  *(bf4*)dst = o;
}

__global__ __launch_bounds__(256) void k_attn_eagg(const float* __restrict__ ent,
                                                   const unsigned char* __restrict__ pmask,
                                                   const __hip_bfloat16* __restrict__ Ubf,
                                                   const float* __restrict__ cvec,
                                                   __hip_bfloat16* __restrict__ eagg) {
  __shared__ __hip_bfloat16 ent_s[kE][kD + 8];      // pitch 1032
  __shared__ float sred[4][kE][kH + 1];             // per-wave partial S^T[e][h]
  __shared__ __hip_bfloat16 attn_b[kH][32];         // attn[h][e], cols 16..31 zero
  int sb = blockIdx.x;
  int s = sb >> 5, b = sb & 31;
  int t = threadIdx.x, l = t & 63, w = t >> 6;
  int quad = l >> 4, lane16 = l & 15;

  // ---- stage E x D entity tile -> LDS bf16 ----
  const float* src = ent + (size_t)(s * kE) * kB * kD + (size_t)b * kD;
  #pragma unroll
  for (int it = 0; it < 8; it++) {
    int i = t + it * 256;
    int e = i >> 7, f = (i & 127) * 8;
    const float4* pp = (const float4*)(src + (size_t)e * kB * kD + f);
    float4 v0 = pp[0], v1 = pp[1];
    bf8v pk;
    pk.v[0] = __float2bfloat16(v0.x); pk.v[1] = __float2bfloat16(v0.y);
    pk.v[2] = __float2bfloat16(v0.z); pk.v[3] = __float2bfloat16(v0.w);
    pk.v[4] = __float2bfloat16(v1.x); pk.v[5] = __float2bfloat16(v1.y);
    pk.v[6] = __float2bfloat16(v1.z); pk.v[7] = __float2bfloat16(v1.w);
    *(bf8v*)&ent_s[e][f] = pk;
  }
  __syncthreads();

  // ---- scores: S^T[e,h] = sum_d ent[e,d]*U[h,d]; K-split 256 per wave ----
  fvec4 sacc = {};
  #pragma unroll
  for (int ks = 0; ks < 8; ks++) {
    int k0 = w * 256 + ks * 32 + quad * 8;
    bfvec8 a = *(const bfvec8*)&ent_s[lane16][k0];
    bfvec8 bb = *(const bfvec8*)&Ubf[(size_t)lane16 * kD + k0];
    sacc = __builtin_amdgcn_mfma_f32_16x16x32_bf16(a, bb, sacc, 0, 0, 0);
  }
  #pragma unroll
  for (int i = 0; i < 4; i++) sred[w][quad * 4 + i][lane16] = sacc[i];
  __syncthreads();

  // ---- softmax over e (thread t: h = t>>4, e = t&15) ----
  {
    int h = t >> 4, e = t & 15;
    float sc = sred[0][e][h] + sred[1][e][h] + sred[2][e][h] + sred[3][e][h] + cvec[h];
    if (pmask[(size_t)(s * kE + e) * kB + b]) sc = -INFINITY;
    float m = sc;
    #pragma unroll
    for (int o = 8; o >= 1; o >>= 1) m = fmaxf(m, __shfl_xor(m, o, 16));
    float ex = __expf(sc - m);
    float sum = ex;
    #pragma unroll
    for (int o = 8; o >= 1; o >>= 1) sum += __shfl_xor(sum, o, 16);
    attn_b[h][e] = __float2bfloat16(ex / sum);
    attn_b[h][e + 16] = __float2bfloat16(0.f);
  }
  __syncthreads();

  // ---- eagg: D[m=d16][n=h] = sum_e ent^T[d,e]*attn[h,e]; 8 tile-PAIRS per wave ----
  bfvec8 bfrag = *(const bfvec8*)&attn_b[lane16][quad * 8];
  __hip_bfloat16* dst = eagg + (size_t)sb * (kH * kD);
  int eq = (quad & 1) * 8;                       // e-subrange this lane loads
  #pragma unroll
  for (int tp = 0; tp < 8; tp++) {
    int tSel = (quad < 2) ? tp : (tp + 8);       // quads 0,1: tile tp; 2,3: tile tp+8
    int dme = (w * 16 + tSel) * 16 + lane16;
    bfvec8 val;
    #pragma unroll
    for (int j = 0; j < 8; j++)
      val[j] = *(const short*)&ent_s[eq + j][dme];
    ivec4 vi = __builtin_bit_cast(ivec4, val);
    ivec4 wi;
    #pragma unroll
    for (int r = 0; r < 4; r++) wi[r] = __shfl_xor(vi[r], 32);
    bfvec8 valB = __builtin_bit_cast(bfvec8, wi);
    fvec4 aA = {}, aB = {};
    aA = __builtin_amdgcn_mfma_f32_16x16x32_bf16(val,  bfrag, aA, 0, 0, 0);
    aB = __builtin_amdgcn_mfma_f32_16x16x32_bf16(valB, bfrag, aB, 0, 0, 0);
    int d0A = (w * 16 + tp) * 16 + quad * 4;
    int d0B = (w * 16 + tp + 8) * 16 + quad * 4;
    st4(&dst[(size_t)lane16 * kD + d0A], aA);
    st4(&dst[(size_t)lane16 * kD + d0B], aB);
  }
}

// ---------------- staging convert helper ----------------
__device__ __forceinline__ void cvt8(__hip_bfloat16* s, float4 v0, float4 v1) {
  bf8v pk;
  pk.v[0] = __float2bfloat16(v0.x); pk.v[1] = __float2bfloat16(v0.y);
  pk.v[2] = __float2bfloat16(v0.z); pk.v[3] = __float2bfloat16(v0.w);
  pk.v[4] = __float2bfloat16(v1.x); pk.v[5] = __float2bfloat16(v1.y);
  pk.v[6] = __float2bfloat16(v1.z); pk.v[7] = __float2bfloat16(v1.w);
  *(bf8v*)s = pk;
}

// ---------------- bf16 MFMA GEMM (NT), 64x64 tile, double-buffered ----------------
// MODE 0: f32 out. MODE 2: bf16 out. Bias added if non-null.
// T3-minimum pipeline: next-tile reg prefetch before the single per-iter barrier.

template <int MODE, typename TC>
__global__ __launch_bounds__(256) void k_gemm_mfma(
    const __hip_bfloat16* __restrict__ Abase, int lda, long aBatch,
    const __hip_bfloat16* __restrict__ Bbase, int ldb, long bBatch,
    TC* __restrict__ Cbase, int ldc, long cBatch,
    const float* __restrict__ bias, long biasBatch, int Ksz) {
  // bijective XCD swizzle (nwg % 8 == 0 for all our launches)
  int nwg = gridDim.x * gridDim.y * gridDim.z;
  int wgid = blockIdx.x + gridDim.x * (blockIdx.y + gridDim.y * blockIdx.z);
  int per = nwg >> 3;
  int swz = (wgid & 7) * per + (wgid >> 3);
  int bx = swz % gridDim.x;
  int rr = swz / gridDim.x;
  int by = rr % gridDim.y;
  int bz = rr / gridDim.y;
  const __hip_bfloat16* Ag = Abase + (size_t)bz * aBatch;
  const __hip_bfloat16* Bg = Bbase + (size_t)bz * bBatch;
  TC* Cg = Cbase + (size_t)bz * cBatch;
  const float* biasp = bias ? bias + (size_t)bz * biasBatch : nullptr;
  const int m0 = bx * 64, n0 = by * 64;
  __shared__ __hip_bfloat16 As[2][64][72];
  __shared__ __hip_bfloat16 Bs[2][64][72];
  const int t = threadIdx.x;
  const int l = t & 63, w = t >> 6;
  const int quad = l >> 4, col = l & 15;
  const int row0 = t >> 3, kq = (t & 7) * 8;      // chunk 0; chunk 1 = row0+32
  fvec4 acc[4] = {};
  bf8v ra0, ra1, rb0, rb1;
  auto LDT = [&](int k0) {
    ra0 = *(const bf8v*)(Ag + (size_t)(m0 + row0) * lda + k0 + kq);
    ra1 = *(const bf8v*)(Ag + (size_t)(m0 + row0 + 32) * lda + k0 + kq);
    rb0 = *(const bf8v*)(Bg + (size_t)(n0 + row0) * ldb + k0 + kq);
    rb1 = *(const bf8v*)(Bg + (size_t)(n0 + row0 + 32) * ldb + k0 + kq);
  };
  auto STT = [&](int buf) {
    *(bf8v*)&As[buf][row0][kq] = ra0;
    *(bf8v*)&As[buf][row0 + 32][kq] = ra1;
    *(bf8v*)&Bs[buf][row0][kq] = rb0;
    *(bf8v*)&Bs[buf][row0 + 32][kq] = rb1;
  };
  LDT(0); STT(0);
  int cur = 0;
  for (int k0 = 0; k0 < Ksz; k0 += 64) {
    bool more = (k0 + 64) < Ksz;
    if (more) LDT(k0 + 64);          // loads in flight across the barrier
    __syncthreads();                 // buf[cur] ready (written pre-loop or prev iter)
    #pragma unroll
    for (int ks = 0; ks < 64; ks += 32) {
      bfvec8 a = *(const bfvec8*)&As[cur][w * 16 + col][ks + quad * 8];
      #pragma unroll
      for (int nt = 0; nt < 4; nt++) {
        bfvec8 b = *(const bfvec8*)&Bs[cur][nt * 16 + col][ks + quad * 8];
        acc[nt] = __builtin_amdgcn_mfma_f32_16x16x32_bf16(a, b, acc[nt], 0, 0, 0);
      }
    }
    if (more) STT(cur ^ 1);          // write OTHER buffer: no race with readers of cur
    cur ^= 1;
  }
  #pragma unroll
  for (int nt = 0; nt < 4; nt++) {
    int n = n0 + nt * 16 + col;
    float bv = biasp ? biasp[n] : 0.f;
    #pragma unroll
    for (int i = 0; i < 4; i++) {
      int r = m0 + w * 16 + quad * 4 + i;
      float v = acc[nt][i] + bv;
      if constexpr (MODE == 0) ((float*)Cg)[(size_t)r * ldc + n] = v;
      else ((__hip_bfloat16*)Cg)[(size_t)r * ldc + n] = __float2bfloat16(v);
    }
  }
}

// ---------------- bf16 MFMA GEMM (NN, f32 in, bf16 out), dbuf, z-batched pair ----------------
// z=0: C0 = A0 @ B0 ; z=1: C1 = A1 @ B1.  All operands 1024-stride.

__global__ __launch_bounds__(256) void k_gemm_nn(
    const float* __restrict__ A0, const float* __restrict__ B0,
    const float* __restrict__ A1, const float* __restrict__ B1,
    __hip_bfloat16* __restrict__ C0, __hip_bfloat16* __restrict__ C1, int Ksz) {
  int nwg = gridDim.x * gridDim.y * gridDim.z;
  int wgid = blockIdx.x + gridDim.x * (blockIdx.y + gridDim.y * blockIdx.z);
  int per = nwg >> 3;
  int swz = (wgid & 7) * per + (wgid >> 3);
  int bx = swz % gridDim.x;
  int rr = swz / gridDim.x;
  int by = rr % gridDim.y;
  int bz = rr / gridDim.y;
  const float* Ag = bz ? A1 : A0;
  const float* Bg = bz ? B1 : B0;
  __hip_bfloat16* Cg = bz ? C1 : C0;
  const int m0 = bx * 64, n0 = by * 64;
  __shared__ __hip_bfloat16 As[2][64][72];
  __shared__ __hip_bfloat16 Bs[2][64][72];
  const int t = threadIdx.x;
  const int l = t & 63, w = t >> 6;
  const int quad = l >> 4, col = l & 15;
  const int row0 = t >> 3, kq = (t & 7) * 8;
  fvec4 acc[4] = {};
  float4 a00, a01, a10, a11, b00, b01, b10, b11;
  auto LDT = [&](int k0) {
    const float4* p0 = (const float4*)(Ag + (size_t)(m0 + row0) * kD + k0 + kq);
    a00 = p0[0]; a01 = p0[1];
    const float4* p1 = (const float4*)(Ag + (size_t)(m0 + row0 + 32) * kD + k0 + kq);
    a10 = p1[0]; a11 = p1[1];
    const float4* q0 = (const float4*)(Bg + (size_t)(k0 + row0) * kD + n0 + kq);
    b00 = q0[0]; b01 = q0[1];
    const float4* q1 = (const float4*)(Bg + (size_t)(k0 + row0 + 32) * kD + n0 + kq);
    b10 = q1[0]; b11 = q1[1];
  };
  auto STT = [&](int buf) {
    cvt8(&As[buf][row0][kq], a00, a01);
    cvt8(&As[buf][row0 + 32][kq], a10, a11);
    Bs[buf][kq + 0][row0] = __float2bfloat16(b00.x);
    Bs[buf][kq + 1][row0] = __float2bfloat16(b00.y);
    Bs[buf][kq + 2][row0] = __float2bfloat16(b00.z);
    Bs[buf][kq + 3][row0] = __float2bfloat16(b00.w);
    Bs[buf][kq + 4][row0] = __float2bfloat16(b01.x);
    Bs[buf][kq + 5][row0] = __float2bfloat16(b01.y);
    Bs[buf][kq + 6][row0] = __float2bfloat16(b01.z);
    Bs[buf][kq + 7][row0] = __float2bfloat16(b01.w);
    Bs[buf][kq + 0][row0 + 32] = __float2bfloat16(b10.x);
    Bs[buf][kq + 1][row0 + 32] = __float2bfloat16(b10.y);
    Bs[buf][kq + 2][row0 + 32] = __float2bfloat16(b10.z);
    Bs[buf][kq + 3][row0 + 32] = __float2bfloat16(b10.w);
    Bs[buf][kq + 4][row0 + 32] = __float2bfloat16(b11.x);
    Bs[buf][kq + 5][row0 + 32] = __float2bfloat16(b11.y);
    Bs[buf][kq + 6][row0 + 32] = __float2bfloat16(b11.z);
    Bs[buf][kq + 7][row0 + 32] = __float2bfloat16(b11.w);
  };
  LDT(0); STT(0);
  int cur = 0;
  for (int k0 = 0; k0 < Ksz; k0 += 64) {
    bool more = (k0 + 64) < Ksz;
    if (more) LDT(k0 + 64);
    __syncthreads();
    #pragma unroll
    for (int ks = 0; ks < 64; ks += 32) {
      bfvec8 a = *(const bfvec8*)&As[cur][w * 16 + col][ks + quad * 8];
      #pragma unroll
      for (int nt = 0; nt < 4; nt++) {
        bfvec8 b = *(const bfvec8*)&Bs[cur][nt * 16 + col][ks + quad * 8];
        acc[nt] = __builtin_amdgcn_mfma_f32_16x16x32_bf16(a, b, acc[nt], 0, 0, 0);
      }
    }
    if (more) STT(cur ^ 1);
    cur ^= 1;
  }
  #pragma unroll
  for (int nt = 0; nt < 4; nt++) {
    int n = n0 + nt * 16 + col;
    #pragma unroll
    for (int i = 0; i < 4; i++) {
      int r = m0 + w * 16 + quad * 4 + i;
      Cg[(size_t)r * kD + n] = __float2bfloat16(acc[nt][i]);
    }
  }
}

extern "C" void kernel_launch(void* const* d_in, const int* in_sizes, int n_in,
                              void* d_out, int out_size, void* d_ws, size_t ws_size,
                              hipStream_t stream) {
  const float* ent            = (const float*)d_in[0];
  const unsigned char* pmask  = (const unsigned char*)d_in[1];
  const float* query          = (const float*)d_in[3];
  const float* Wk_lin         = (const float*)d_in[4];
  const float* bk_lin         = (const float*)d_in[5];
  const float* Wv_lin         = (const float*)d_in[6];
  const float* bv_lin         = (const float*)d_in[7];
  const float* Wq_in          = (const float*)d_in[8];
  const float* bq_in          = (const float*)d_in[9];
  const float* Wk_in          = (const float*)d_in[10];
  const float* bk_in          = (const float*)d_in[11];
  const float* Wv_in          = (const float*)d_in[12];
  const float* bv_in          = (const float*)d_in[13];
  const float* Wo             = (const float*)d_in[14];
  const float* bo             = (const float*)d_in[15];
  float* out = (float*)d_out;

  float* p = (float*)d_ws;
  float* qs   = p; p += 1024;            // scaled projected query
  float* cvec = p; p += 256;             // c[h]
  float* cb   = p; p += kD;              // Wv_in@bv_lin + bv_in
  float* kb2  = p; p += kD;              // Wk_in@bk_lin + bk_in
  __hip_bfloat16* bp = (__hip_bfloat16*)p;
  __hip_bfloat16* Ubf  = bp; bp += (size_t)kH * kD;    // U[h][d] bf16
  __hip_bfloat16* Mmat = bp; bp += (size_t)kD * kD;    // Wv_in @ Wv_lin bf16
  __hip_bfloat16* KKbf = bp; bp += (size_t)kD * kD;    // Wk_in @ Wk_lin bf16
  __hip_bfloat16* Wobf = bp; bp += (size_t)kD * kD;    // Wo bf16
  __hip_bfloat16* ctx2 = bp; bp += (size_t)kSB * kD;   // ctx bf16 [SB, D]
  __hip_bfloat16* eagg = bp;                           // [SB, H, D] bf16

  // ---- precompute (6 dispatches total incl. main pipeline) ----
  k_pre<<<4096, 256, 0, stream>>>(Wq_in, query, bq_in, Wv_in, bv_lin, bv_in,
                                  Wk_in, bk_lin, bk_in, Wo, qs, cb, kb2, Wobf);
  // z=0: Mmat = Wv_in @ Wv_lin ; z=1: KK = Wk_in @ Wk_lin (both bf16 out)
  k_gemm_nn<<<dim3(16, 16, 2), 256, 0, stream>>>(Wv_in, Wv_lin, Wk_in, Wk_lin,
                                                 Mmat, KKbf, kD);
  // U = qs @ KK (row-weighted sum), cvec = qs·kb2 per head
  k_w2p<<<64, 256, 0, stream>>>(qs, KKbf, kb2, Ubf, cvec);

  // ---- main pipeline ----
  k_attn_eagg<<<kSB, 256, 0, stream>>>(ent, pmask, Ubf, cvec, eagg);
  // ctx[sb, h*64+j] = M_h @ eagg[sb,h,:] + cb   (batched over h = z), bf16 out
  k_gemm_mfma<2, __hip_bfloat16><<<dim3(kSB / 64, 1, kH), 256, 0, stream>>>(
      eagg, kH * kD, (long)kD, Mmat, kD, (long)(kHD * kD),
      ctx2, kD, (long)kHD, cb, (long)kHD, kD);
  // out = ctx @ Wo^T + bo
  k_gemm_mfma<0, float><<<dim3(kSB / 64, kD / 64, 1), 256, 0, stream>>>(
      ctx2, kD, 0L, Wobf, kD, 0L, out, kD, 0L, bo, 0L, kD);
}

// Round 4
// 337.531 us; speedup vs baseline: 1.1558x; 1.1558x over previous
//
#include <hip/hip_runtime.h>
#include <hip/hip_bf16.h>

constexpr int kD  = 1024;
constexpr int kH  = 16;
constexpr int kHD = 64;
constexpr int kS  = 64;
constexpr int kE  = 16;
constexpr int kB  = 32;
constexpr int kSB = kS * kB;   // 2048 (s,b) pairs

typedef __attribute__((ext_vector_type(8))) short bfvec8;   // 8 bf16 (4 VGPRs)
typedef __attribute__((ext_vector_type(4))) float fvec4;    // MFMA acc

struct __align__(8)  bf4  { __hip_bfloat16 v[4]; };
struct __align__(16) bf8v { __hip_bfloat16 v[8]; };

// ---------------- merged precompute: wmat+cvec / cb / Wobf ----------------
// blocks 0..63     : h = j>>2, chunk = j&3.
//    qs row-dots recomputed in-block (4-lane split, coalesced), then
//    wmat[h, chunk*256+t] = sum_j qs[hj] * Wk_in[hj, d];
//    chunk 0 additionally: cvec[h] = sum_j qs[hj]*(Wk_in[hj]·bk_lin + bk_in[hj])
// blocks 64..1087  : cb[row] = Wv_in[row,:]·bv_lin + bv_in[row]
// blocks 1088..2111: Wobf row convert (f32 -> bf16)
__global__ __launch_bounds__(256) void k_pre2(const float* __restrict__ Wq_in,
                                              const float* __restrict__ query,
                                              const float* __restrict__ bq_in,
                                              const float* __restrict__ Wv_in,
                                              const float* __restrict__ bv_lin,
                                              const float* __restrict__ bv_in,
                                              const float* __restrict__ Wk_in,
                                              const float* __restrict__ bk_lin,
                                              const float* __restrict__ bk_in,
                                              const float* __restrict__ Wo,
                                              float* __restrict__ wmat,
                                              float* __restrict__ cvec,
                                              float* __restrict__ cb,
                                              __hip_bfloat16* __restrict__ Wobf) {
  int j = blockIdx.x, t = threadIdx.x;
  if (j < 64) {
    int h = j >> 2, chunk = j & 3;
    __shared__ float qs_s[64];
    __shared__ float kb2_s[64];
    int l = t & 63, w = t >> 6;
    int jj = w * 16 + (l >> 2);          // j-row within head (0..63)
    int part = l & 3;                    // 4 lanes split the 1024-dot
    {
      const float4* w4 = (const float4*)(Wq_in + (size_t)(h * 64 + jj) * kD);
      const float4* q4 = (const float4*)query;
      float acc = 0.f;
      #pragma unroll 4
      for (int i = 0; i < 64; i++) {
        float4 a = w4[part + 4 * i], b = q4[part + 4 * i];
        acc += a.x * b.x + a.y * b.y + a.z * b.z + a.w * b.w;
      }
      acc += __shfl_xor(acc, 1);
      acc += __shfl_xor(acc, 2);
      if (part == 0) qs_s[jj] = (acc + bq_in[h * 64 + jj]) * 0.125f;
    }
    if (chunk == 0) {
      const float4* w4 = (const float4*)(Wk_in + (size_t)(h * 64 + jj) * kD);
      const float4* q4 = (const float4*)bk_lin;
      float acc = 0.f;
      #pragma unroll 4
      for (int i = 0; i < 64; i++) {
        float4 a = w4[part + 4 * i], b = q4[part + 4 * i];
        acc += a.x * b.x + a.y * b.y + a.z * b.z + a.w * b.w;
      }
      acc += __shfl_xor(acc, 1);
      acc += __shfl_xor(acc, 2);
      if (part == 0) kb2_s[jj] = acc + bk_in[h * 64 + jj];
    }
    __syncthreads();
    int d = chunk * 256 + t;
    float acc = 0.f;
    #pragma unroll 8
    for (int jr = 0; jr < 64; jr++)
      acc = fmaf(qs_s[jr], Wk_in[(size_t)(h * 64 + jr) * kD + d], acc);
    wmat[(size_t)h * kD + d] = acc;
    if (chunk == 0 && t < 64) {
      float v = qs_s[t] * kb2_s[t];
      #pragma unroll
      for (int o = 32; o >= 1; o >>= 1) v += __shfl_xor(v, o);
      if (t == 0) cvec[h] = v;
    }
    return;
  }
  if (j < 1088) {                        // cb row
    int row = j - 64;
    const float4* w4 = (const float4*)(Wv_in + (size_t)row * kD);
    const float4* v4 = (const float4*)bv_lin;
    float4 a = w4[t], b = v4[t];
    float acc = a.x * b.x + a.y * b.y + a.z * b.z + a.w * b.w;
    #pragma unroll
    for (int o = 32; o >= 1; o >>= 1) acc += __shfl_xor(acc, o);
    __shared__ float red[4];
    if ((t & 63) == 0) red[t >> 6] = acc;
    __syncthreads();
    if (t == 0) cb[row] = red[0] + red[1] + red[2] + red[3] + bv_in[row];
    return;
  }
  // Wobf convert: one row per block, 4 elems/thread
  int i = (j - 1088) * kD + t * 4;
  float4 v = *(const float4*)(Wo + i);
  bf4 o;
  o.v[0] = __float2bfloat16(v.x); o.v[1] = __float2bfloat16(v.y);
  o.v[2] = __float2bfloat16(v.z); o.v[3] = __float2bfloat16(v.w);
  *(bf4*)(Wobf + i) = o;
}

// ---------------- fused attention: scores(MFMA) -> softmax -> eagg(MFMA) ----------------
// (R0 proven version, byte-identical)

__global__ __launch_bounds__(256) void k_attn_eagg(const float* __restrict__ ent,
                                                   const unsigned char* __restrict__ pmask,
                                                   const __hip_bfloat16* __restrict__ Ubf,
                                                   const float* __restrict__ cvec,
                                                   __hip_bfloat16* __restrict__ eagg) {
  __shared__ __hip_bfloat16 ent_s[kE][kD + 8];      // pitch 1032
  __shared__ float sred[4][kE][kH + 1];             // per-wave partial S^T[e][h]
  __shared__ __hip_bfloat16 attn_b[kH][32];         // attn[h][e], cols 16..31 zero
  int sb = blockIdx.x;
  int s = sb >> 5, b = sb & 31;
  int t = threadIdx.x, l = t & 63, w = t >> 6;
  int quad = l >> 4, lane16 = l & 15;

  // ---- stage E x D entity tile -> LDS bf16 ----
  const float* src = ent + (size_t)(s * kE) * kB * kD + (size_t)b * kD;
  #pragma unroll
  for (int it = 0; it < 8; it++) {
    int i = t + it * 256;
    int e = i >> 7, f = (i & 127) * 8;
    const float4* pp = (const float4*)(src + (size_t)e * kB * kD + f);
    float4 v0 = pp[0], v1 = pp[1];
    bf8v pk;
    pk.v[0] = __float2bfloat16(v0.x); pk.v[1] = __float2bfloat16(v0.y);
    pk.v[2] = __float2bfloat16(v0.z); pk.v[3] = __float2bfloat16(v0.w);
    pk.v[4] = __float2bfloat16(v1.x); pk.v[5] = __float2bfloat16(v1.y);
    pk.v[6] = __float2bfloat16(v1.z); pk.v[7] = __float2bfloat16(v1.w);
    *(bf8v*)&ent_s[e][f] = pk;
  }
  __syncthreads();

  // ---- scores: S^T[e,h] = sum_d ent[e,d]*U[h,d]; K-split 256 per wave ----
  fvec4 sacc = {};
  #pragma unroll
  for (int ks = 0; ks < 8; ks++) {
    int k0 = w * 256 + ks * 32 + quad * 8;
    bfvec8 a = *(const bfvec8*)&ent_s[lane16][k0];
    bfvec8 bb = *(const bfvec8*)&Ubf[(size_t)lane16 * kD + k0];
    sacc = __builtin_amdgcn_mfma_f32_16x16x32_bf16(a, bb, sacc, 0, 0, 0);
  }
  #pragma unroll
  for (int i = 0; i < 4; i++) sred[w][quad * 4 + i][lane16] = sacc[i];
  __syncthreads();

  // ---- softmax over e (thread t: h = t>>4, e = t&15) ----
  {
    int h = t >> 4, e = t & 15;
    float sc = sred[0][e][h] + sred[1][e][h] + sred[2][e][h] + sred[3][e][h] + cvec[h];
    if (pmask[(size_t)(s * kE + e) * kB + b]) sc = -INFINITY;
    float m = sc;
    #pragma unroll
    for (int o = 8; o >= 1; o >>= 1) m = fmaxf(m, __shfl_xor(m, o, 16));
    float ex = __expf(sc - m);
    float sum = ex;
    #pragma unroll
    for (int o = 8; o >= 1; o >>= 1) sum += __shfl_xor(sum, o, 16);
    attn_b[h][e] = __float2bfloat16(ex / sum);
    attn_b[h][e + 16] = __float2bfloat16(0.f);
  }
  __syncthreads();

  // ---- eagg: D[m=d16][n=h] = sum_e ent^T[d,e]*attn[h,e]; 16 d-tiles per wave ----
  bfvec8 bfrag = *(const bfvec8*)&attn_b[lane16][quad * 8];
  __hip_bfloat16* dst = eagg + (size_t)sb * (kH * kD);
  for (int tt = 0; tt < 16; tt++) {
    int dme = (w * 16 + tt) * 16 + lane16;
    bfvec8 afrag = {};
    if (quad < 2) {
      #pragma unroll
      for (int j = 0; j < 8; j++)
        afrag[j] = *(const short*)&ent_s[quad * 8 + j][dme];
    }
    fvec4 acc = {};
    acc = __builtin_amdgcn_mfma_f32_16x16x32_bf16(afrag, bfrag, acc, 0, 0, 0);
    int d0 = (w * 16 + tt) * 16 + quad * 4;
    bf4 o;
    o.v[0] = __float2bfloat16(acc[0]); o.v[1] = __float2bfloat16(acc[1]);
    o.v[2] = __float2bfloat16(acc[2]); o.v[3] = __float2bfloat16(acc[3]);
    *(bf4*)&dst[(size_t)lane16 * kD + d0] = o;
  }
}

// ---------------- staging helpers ----------------

__device__ __forceinline__ void stage_row(const __hip_bfloat16* g, __hip_bfloat16* s) {
  *(bf8v*)s = *(const bf8v*)g;
}
__device__ __forceinline__ void stage_row(const float* g, __hip_bfloat16* s) {
  const float4* p = (const float4*)g;
  float4 v0 = p[0], v1 = p[1];
  bf8v pk;
  pk.v[0] = __float2bfloat16(v0.x); pk.v[1] = __float2bfloat16(v0.y);
  pk.v[2] = __float2bfloat16(v0.z); pk.v[3] = __float2bfloat16(v0.w);
  pk.v[4] = __float2bfloat16(v1.x); pk.v[5] = __float2bfloat16(v1.y);
  pk.v[6] = __float2bfloat16(v1.z); pk.v[7] = __float2bfloat16(v1.w);
  *(bf8v*)s = pk;
}

// ---------------- bf16 MFMA GEMM (NT), 64x64 tile (R0 proven) ----------------
// MODE 0: f32 out. MODE 2: bf16 out. Bias added if non-null.

template <int MODE, typename TA, typename TB, typename TC>
__global__ __launch_bounds__(256) void k_gemm_mfma(
    const TA* __restrict__ Abase, int lda, long aBatch,
    const TB* __restrict__ Bbase, int ldb, long bBatch,
    TC* __restrict__ Cbase, int ldc, long cBatch,
    const float* __restrict__ bias, long biasBatch, int Ksz) {
  const TA* Ag = Abase + (size_t)blockIdx.z * aBatch;
  const TB* Bg = Bbase + (size_t)blockIdx.z * bBatch;
  TC* Cg = Cbase + (size_t)blockIdx.z * cBatch;
  const float* biasp = bias ? bias + (size_t)blockIdx.z * biasBatch : nullptr;
  const int m0 = blockIdx.x * 64, n0 = blockIdx.y * 64;
  __shared__ __hip_bfloat16 As[64][72];
  __shared__ __hip_bfloat16 Bs[64][72];
  const int t = threadIdx.x;
  const int l = t & 63, w = t >> 6;
  const int quad = l >> 4, col = l & 15;
  fvec4 acc[4] = {};
  for (int k0 = 0; k0 < Ksz; k0 += 64) {
    #pragma unroll
    for (int c = t; c < 512; c += 256) {
      int row = c >> 3, kq = (c & 7) * 8;
      stage_row(Ag + (size_t)(m0 + row) * lda + k0 + kq, &As[row][kq]);
      stage_row(Bg + (size_t)(n0 + row) * ldb + k0 + kq, &Bs[row][kq]);
    }
    __syncthreads();
    #pragma unroll
    for (int ks = 0; ks < 64; ks += 32) {
      bfvec8 a = *(const bfvec8*)&As[w * 16 + col][ks + quad * 8];
      #pragma unroll
      for (int nt = 0; nt < 4; nt++) {
        bfvec8 b = *(const bfvec8*)&Bs[nt * 16 + col][ks + quad * 8];
        acc[nt] = __builtin_amdgcn_mfma_f32_16x16x32_bf16(a, b, acc[nt], 0, 0, 0);
      }
    }
    __syncthreads();
  }
  #pragma unroll
  for (int nt = 0; nt < 4; nt++) {
    int n = n0 + nt * 16 + col;
    float bv = biasp ? biasp[n] : 0.f;
    #pragma unroll
    for (int i = 0; i < 4; i++) {
      int r = m0 + w * 16 + quad * 4 + i;
      float v = acc[nt][i] + bv;
      if constexpr (MODE == 0) ((float*)Cg)[(size_t)r * ldc + n] = v;
      else ((__hip_bfloat16*)Cg)[(size_t)r * ldc + n] = __float2bfloat16(v);
    }
  }
}

// ---------------- bf16 MFMA GEMM (NN, f32 in, bf16 out), 64x64 tile (R0 proven) ----------------
// C[m,n] = sum_k A[m,k]*B[k,n].  B transposed+converted during LDS staging.
// Merged launch: blockIdx.x < 16 -> (A0,B0,C0) [Mmat]; blockIdx.x == 16 -> (A1,B1,C1) [U].

__global__ __launch_bounds__(256) void k_gemm_nn(
    const float* __restrict__ A0, const float* __restrict__ B0,
    __hip_bfloat16* __restrict__ C0,
    const float* __restrict__ A1, const float* __restrict__ B1,
    __hip_bfloat16* __restrict__ C1, int Ksz) {
  const bool isU = (blockIdx.x == 16);
  const float* Ag = isU ? A1 : A0;
  const float* Bg = isU ? B1 : B0;
  __hip_bfloat16* Cg = isU ? C1 : C0;
  const int m0 = isU ? 0 : blockIdx.x * 64, n0 = blockIdx.y * 64;
  __shared__ __hip_bfloat16 As[64][72];
  __shared__ __hip_bfloat16 Bs[64][72];
  const int t = threadIdx.x;
  const int l = t & 63, w = t >> 6;
  const int quad = l >> 4, col = l & 15;
  fvec4 acc[4] = {};
  for (int k0 = 0; k0 < Ksz; k0 += 64) {
    #pragma unroll
    for (int c = t; c < 512; c += 256) {
      int row = c >> 3, kq = (c & 7) * 8;
      stage_row(Ag + (size_t)(m0 + row) * kD + k0 + kq, &As[row][kq]);
      // B row k0+row, cols n0+kq..+7 -> Bs[n][k] (scalar transposed writes)
      const float4* pb = (const float4*)(Bg + (size_t)(k0 + row) * kD + n0 + kq);
      float4 b0 = pb[0], b1 = pb[1];
      Bs[kq + 0][row] = __float2bfloat16(b0.x);
      Bs[kq + 1][row] = __float2bfloat16(b0.y);
      Bs[kq + 2][row] = __float2bfloat16(b0.z);
      Bs[kq + 3][row] = __float2bfloat16(b0.w);
      Bs[kq + 4][row] = __float2bfloat16(b1.x);
      Bs[kq + 5][row] = __float2bfloat16(b1.y);
      Bs[kq + 6][row] = __float2bfloat16(b1.z);
      Bs[kq + 7][row] = __float2bfloat16(b1.w);
    }
    __syncthreads();
    #pragma unroll
    for (int ks = 0; ks < 64; ks += 32) {
      bfvec8 a = *(const bfvec8*)&As[w * 16 + col][ks + quad * 8];
      #pragma unroll
      for (int nt = 0; nt < 4; nt++) {
        bfvec8 b = *(const bfvec8*)&Bs[nt * 16 + col][ks + quad * 8];
        acc[nt] = __builtin_amdgcn_mfma_f32_16x16x32_bf16(a, b, acc[nt], 0, 0, 0);
      }
    }
    __syncthreads();
  }
  #pragma unroll
  for (int nt = 0; nt < 4; nt++) {
    int n = n0 + nt * 16 + col;
    #pragma unroll
    for (int i = 0; i < 4; i++) {
      int r = m0 + w * 16 + quad * 4 + i;
      Cg[(size_t)r * kD + n] = __float2bfloat16(acc[nt][i]);
    }
  }
}

extern "C" void kernel_launch(void* const* d_in, const int* in_sizes, int n_in,
                              void* d_out, int out_size, void* d_ws, size_t ws_size,
                              hipStream_t stream) {
  const float* ent            = (const float*)d_in[0];
  const unsigned char* pmask  = (const unsigned char*)d_in[1];
  const float* query          = (const float*)d_in[3];
  const float* Wk_lin         = (const float*)d_in[4];
  const float* bk_lin         = (const float*)d_in[5];
  const float* Wv_lin         = (const float*)d_in[6];
  const float* bv_lin         = (const float*)d_in[7];
  const float* Wq_in          = (const float*)d_in[8];
  const float* bq_in          = (const float*)d_in[9];
  const float* Wk_in          = (const float*)d_in[10];
  const float* bk_in          = (const float*)d_in[11];
  const float* Wv_in          = (const float*)d_in[12];
  const float* bv_in          = (const float*)d_in[13];
  const float* Wo             = (const float*)d_in[14];
  const float* bo             = (const float*)d_in[15];
  float* out = (float*)d_out;

  float* p = (float*)d_ws;
  float* wmat = p; p += 64 * kD;         // w[h,d] rows 0..15 valid
  float* cvec = p; p += 256;             // c[h]
  float* cb   = p; p += kD;              // Wv_in@bv_lin + bv_in
  __hip_bfloat16* bp = (__hip_bfloat16*)p;
  __hip_bfloat16* Ubf  = bp; bp += (size_t)64 * kD;    // U[h][d] bf16 (rows 0..15 valid)
  __hip_bfloat16* Mmat = bp; bp += (size_t)kD * kD;    // Wv_in @ Wv_lin bf16
  __hip_bfloat16* Wobf = bp; bp += (size_t)kD * kD;    // Wo bf16
  __hip_bfloat16* ctx2 = bp; bp += (size_t)kSB * kD;   // ctx bf16 [SB, D]
  __hip_bfloat16* eagg = bp;                           // [SB, H, D] bf16

  // ---- 5 dispatches total ----
  // 1) merged precompute: wmat, cvec, cb, Wobf
  k_pre2<<<2112, 256, 0, stream>>>(Wq_in, query, bq_in, Wv_in, bv_lin, bv_in,
                                   Wk_in, bk_lin, bk_in, Wo,
                                   wmat, cvec, cb, Wobf);
  // 2) merged NN GEMM: bx<16: Mmat = Wv_in @ Wv_lin ; bx==16: U = wmat @ Wk_lin
  k_gemm_nn<<<dim3(17, 16, 1), 256, 0, stream>>>(Wv_in, Wv_lin, Mmat,
                                                 wmat, Wk_lin, Ubf, kD);
  // 3) fused attention + entity aggregation
  k_attn_eagg<<<kSB, 256, 0, stream>>>(ent, pmask, Ubf, cvec, eagg);
  // 4) ctx[sb, h*64+j] = M_h @ eagg[sb,h,:] + cb   (batched over h = z), bf16 out
  k_gemm_mfma<2, __hip_bfloat16, __hip_bfloat16, __hip_bfloat16>
      <<<dim3(kSB / 64, 1, kH), 256, 0, stream>>>(
      eagg, kH * kD, (long)kD, Mmat, kD, (long)(kHD * kD),
      ctx2, kD, (long)kHD, cb, (long)kHD, kD);
  // 5) out = ctx @ Wo^T + bo
  k_gemm_mfma<0, __hip_bfloat16, __hip_bfloat16, float>
      <<<dim3(kSB / 64, kD / 64, 1), 256, 0, stream>>>(
      ctx2, kD, 0L, Wobf, kD, 0L, out, kD, 0L, bo, 0L, kD);
}